// Round 13
// baseline (69.628 us; speedup 1.0000x reference)
//
#include <hip/hip_runtime.h>

// ---------------------------------------------------------------------------
// SNN Perceptron Equalizer (LIF recurrent net), MI355X
//
//  * ff = xt@W_in^T  ->  <=3 precomputed rows P[t][seg][sym][h] (fp64-built).
//  * One WAVE per batch element; lane l holds h=4l..4l+3 (f32x4 state).
//    16 waves / 1024-thread block, 1 block/CU. launch_bounds(1024,4).
//  * The op is L1-PORT-bound: ~(2.5 + c)*1KB rows per wave-step through the
//    64B/cyc CU return port (c ~= 12). Split the WT gather across pipes:
//      - rows 0..143 (56%) staged once in LDS (145KB; separate 128B/cyc pipe)
//      - rows 144..255 from L2
//    Batched synchronous gather, 4+4 per iteration, with COUNT-GUARDED loads:
//    slots beyond the real count are SKIPPED (uniform SALU branch), not
//    redirected to a zero row -- dummy loads cost L1-port cycles even on
//    hits, which is exactly what erased R9's gain. Skipped slots contribute
//    literal 0.0f in the same summation spots -> bit-identical to R9.
//  * z_sum[b,:] = 32*b_out + sum_h cnt[b,h]*W_out[:,h]; rate = spikes/2^25.
// ---------------------------------------------------------------------------

typedef float f32x4 __attribute__((ext_vector_type(4)));

#define T_STEPS 32
#define FDIM    41
#define ODIM    16
#define BDIM    4096
#define MF      164

#define P_FLOATS   (32 * 3 * 16 * 256)
#define WT_ROWS    257                  // row 256 = zeros (safety)
#define WT_FLOATS  (WT_ROWS * 256)
#define WOT_FLOATS (256 * 16)

#define LROWS      144                  // WT rows 0..143 in LDS
#define LBITS      36                   // 4*36 = 144: mask split bit
#define NW         16                   // waves per block

// ---------------------------------------------------------------------------
// K1: build P (fp64 accum), transpose W_rec (+zero row), W_out^T, counter=0.
// blocks 0..383: P; 384..640: W_rec^T (+zero row at 640); 641: W_out^T.
// ---------------------------------------------------------------------------
__global__ __launch_bounds__(256) void k_prep(const float* __restrict__ emb,
                                              const float* __restrict__ W_in,
                                              const float* __restrict__ W_rec,
                                              const float* __restrict__ W_out,
                                              float* __restrict__ P,
                                              float* __restrict__ WT,
                                              float* __restrict__ WOT,
                                              int* __restrict__ counter)
{
    const int bid = blockIdx.x;
    const int tid = threadIdx.x;

    if (bid < 384) {
        const int g  = bid & 3;
        const int ts = bid >> 2;
        const int t  = ts / 3;
        const int si = ts % 3;
        const int k0   = t * MF;
        const int f    = (k0 >> 7) + si;
        const int base = f << 7;
        const int c0   = max(k0, base) - base;
        const int c1   = min(k0 + MF, base + 128) - base;
        const int len  = c1 - c0;

        if (len <= 0) {
            #pragma unroll
            for (int s = 0; s < 4; ++s)
                P[((t * 3 + si) * 16 + 4 * g + s) * 256 + tid] = 0.0f;
            return;
        }

        __shared__ float emb_lds[4][128];
        for (int idx = tid; idx < 4 * 128; idx += 256) {
            const int s = idx >> 7, u = idx & 127;
            if (u < len) emb_lds[s][u] = emb[((4 * g + s) << 7) + c0 + u];
        }
        __syncthreads();

        const int j0 = base + c0 - k0;
        double a0 = 0.0, a1 = 0.0, a2 = 0.0, a3 = 0.0;
        for (int u = 0; u < len; ++u) {
            const double w = (double)W_in[tid * MF + j0 + u];
            a0 += w * (double)emb_lds[0][u];
            a1 += w * (double)emb_lds[1][u];
            a2 += w * (double)emb_lds[2][u];
            a3 += w * (double)emb_lds[3][u];
        }
        P[((t * 3 + si) * 16 + 4 * g + 0) * 256 + tid] = (float)a0;
        P[((t * 3 + si) * 16 + 4 * g + 1) * 256 + tid] = (float)a1;
        P[((t * 3 + si) * 16 + 4 * g + 2) * 256 + tid] = (float)a2;
        P[((t * 3 + si) * 16 + 4 * g + 3) * 256 + tid] = (float)a3;
    } else if (bid < 641) {
        const int h = bid - 384;                // 0..256
        if (h < 256) {
            WT[h * 256 + tid] = W_rec[tid * 256 + h];
        } else {
            WT[256 * 256 + tid] = 0.0f;
            if (tid == 0) *counter = 0;
        }
    } else {
        // W_out^T: WOT[h][o] = W_out[o][h]
        #pragma unroll
        for (int o = 0; o < ODIM; ++o)
            WOT[tid * ODIM + o] = W_out[o * 256 + tid];
    }
}

// ---------------------------------------------------------------------------
// K2: main LIF scan. 256 blocks x 1024 threads (16 waves, wave = batch elem).
// ---------------------------------------------------------------------------
__global__ __launch_bounds__(1024, 4) void k_main(const int* __restrict__ x,
                                                  const float* __restrict__ P,
                                                  const float* __restrict__ WT,
                                                  const float* __restrict__ WOT,
                                                  const float* __restrict__ b_out,
                                                  float* __restrict__ out,
                                                  int* __restrict__ counter)
{
#pragma clang fp contract(off)
    __shared__ f32x4 WTl[(LROWS + 1) * 64];   // 145 KB (row LROWS = zeros)
    __shared__ int   red[NW];

    const int tid  = threadIdx.x;
    const int lane = tid & 63;
    const int wv   = __builtin_amdgcn_readfirstlane(tid >> 6);
    const int b    = blockIdx.x * NW + wv;

    const f32x4* __restrict__ P4  = (const f32x4*)P;
    const f32x4* __restrict__ WT4 = (const f32x4*)WT;

    // stage WT rows 0..143 into LDS (layout identical: row*64 + lane)
    const f32x4 zero4 = {0.f, 0.f, 0.f, 0.f};
    for (int i = tid; i < LROWS * 64; i += 1024) WTl[i] = WT4[i];
    if (tid < 64) WTl[LROWS * 64 + tid] = zero4;   // zero dummy row
    __syncthreads();

    const int xv = (lane < FDIM) ? x[b * FDIM + lane] : 0;

    f32x4 vm = zero4, cur = zero4;
    f32x4 pP0 = zero4, pP1 = zero4, pP2 = zero4;
    unsigned long long sm0 = 0, sm1 = 0, sm2 = 0, sm3 = 0;  // z_{t-1} masks
    int n0 = 0, n1 = 0, n2 = 0, n3 = 0;

    // prologue: ff rows for t=0 (t=0 has 2 segments)
    {
        const int s0 = __builtin_amdgcn_readlane(xv, 0);
        const int s1 = __builtin_amdgcn_readlane(xv, 1);
        pP0 = P4[(0 * 16 + s0) * 64 + lane];
        pP1 = P4[(1 * 16 + s1) * 64 + lane];
    }

    #define PEEL_G(dst)                                                        \
        if (mG0)      { dst = 4*(LBITS+(int)__builtin_ctzll(mG0))+0; mG0 &= mG0-1; } \
        else if (mG1) { dst = 4*(LBITS+(int)__builtin_ctzll(mG1))+1; mG1 &= mG1-1; } \
        else if (mG2) { dst = 4*(LBITS+(int)__builtin_ctzll(mG2))+2; mG2 &= mG2-1; } \
        else if (mG3) { dst = 4*(LBITS+(int)__builtin_ctzll(mG3))+3; mG3 &= mG3-1; }

    #define PEEL_L(dst)                                                        \
        if (mL0)      { dst = 4*(int)__builtin_ctzll(mL0)+0; mL0 &= mL0-1; }   \
        else if (mL1) { dst = 4*(int)__builtin_ctzll(mL1)+1; mL1 &= mL1-1; }   \
        else if (mL2) { dst = 4*(int)__builtin_ctzll(mL2)+2; mL2 &= mL2-1; }   \
        else if (mL3) { dst = 4*(int)__builtin_ctzll(mL3)+3; mL3 &= mL3-1; }

    for (int t = 0; t < T_STEPS; ++t) {
        // 1. membrane decay + spike decision (z_t)
        const f32x4 vdec = vm + 0.1f * (cur - vm);
        const f32x4 idec = cur * 0.8f;
        const bool z0 = vdec.x > 1.0f, z1 = vdec.y > 1.0f,
                   z2 = vdec.z > 1.0f, z3 = vdec.w > 1.0f;
        const unsigned long long nm0 = __ballot(z0), nm1 = __ballot(z1),
                                 nm2 = __ballot(z2), nm3 = __ballot(z3);
        vm.x = z0 ? 0.0f : vdec.x;  vm.y = z1 ? 0.0f : vdec.y;
        vm.z = z2 ? 0.0f : vdec.z;  vm.w = z3 ? 0.0f : vdec.w;
        n0 += z0; n1 += z1; n2 += z2; n3 += z3;

        // 2. rec = z_{t-1} @ W_rec^T : batched sparse gather (LDS + L2),
        //    COUNT-GUARDED loads -- no dummy port traffic.
        f32x4 rec = zero4;
        {
            const unsigned long long LO = (1ULL << LBITS) - 1;
            unsigned long long mL0 = sm0 & LO, mG0 = sm0 >> LBITS;
            unsigned long long mL1 = sm1 & LO, mG1 = sm1 >> LBITS;
            unsigned long long mL2 = sm2 & LO, mG2 = sm2 >> LBITS;
            unsigned long long mL3 = sm3 & LO, mG3 = sm3 >> LBITS;
            int cG = __popcll(mG0) + __popcll(mG1) + __popcll(mG2) + __popcll(mG3);
            int cL = __popcll(mL0) + __popcll(mL1) + __popcll(mL2) + __popcll(mL3);
            while (cG > 0 || cL > 0) {
                int u0 = 256, u1 = 256, u2 = 256, u3 = 256;
                PEEL_G(u0) PEEL_G(u1) PEEL_G(u2) PEEL_G(u3)
                int w0 = LROWS, w1 = LROWS, w2 = LROWS, w3 = LROWS;
                PEEL_L(w0) PEEL_L(w1) PEEL_L(w2) PEEL_L(w3)
                f32x4 a0 = zero4, a1 = zero4, a2 = zero4, a3 = zero4;
                f32x4 b0_ = zero4, b1_ = zero4, b2_ = zero4, b3_ = zero4;
                if (cG > 0) a0 = WT4[u0 * 64 + lane];
                if (cG > 1) a1 = WT4[u1 * 64 + lane];
                if (cG > 2) a2 = WT4[u2 * 64 + lane];
                if (cG > 3) a3 = WT4[u3 * 64 + lane];
                if (cL > 0) b0_ = WTl[w0 * 64 + lane];
                if (cL > 1) b1_ = WTl[w1 * 64 + lane];
                if (cL > 2) b2_ = WTl[w2 * 64 + lane];
                if (cL > 3) b3_ = WTl[w3 * 64 + lane];
                rec += ((a0 + a1) + (a2 + a3)) + ((b0_ + b1_) + (b2_ + b3_));
                cG -= 4;  cL -= 4;
            }
        }

        // 3. new current (ff prefetched last step; i_t uses z_{t-1})
        f32x4 ff = pP0 + pP1;
        if (((t * MF) & 127) > 92) ff += pP2;
        cur = (idec + ff) + rec;

        // 4. issue P rows for t+1 (symbol-only addresses)
        if (t + 1 < T_STEPS) {
            const int tn = t + 1;
            const int f0 = (tn * MF) >> 7;
            const int s0 = __builtin_amdgcn_readlane(xv, f0);
            const int s1 = __builtin_amdgcn_readlane(xv, f0 + 1);
            pP0 = P4[((tn * 3 + 0) * 16 + s0) * 64 + lane];
            pP1 = P4[((tn * 3 + 1) * 16 + s1) * 64 + lane];
            if (((tn * MF) & 127) > 92) {
                const int s2 = __builtin_amdgcn_readlane(xv, f0 + 2);
                pP2 = P4[((tn * 3 + 2) * 16 + s2) * 64 + lane];
            }
        }

        // 5. z_t becomes z_{t-1} for the next step
        sm0 = nm0; sm1 = nm1; sm2 = nm2; sm3 = nm3;
    }
    #undef PEEL_G
    #undef PEEL_L

    // --- epilogue: z_sum[b,o] = 32*b_out[o] + sum_h cnt[h]*W_out[o,h] ---
    // counts live in n0..n3 for h = 4*lane+k; W_out^T + 64-lane butterfly.
    {
        const f32x4* __restrict__ WOT4 = (const f32x4*)WOT; // [256][4] f32x4
        const float fn0 = (float)n0, fn1 = (float)n1,
                    fn2 = (float)n2, fn3 = (float)n3;
        const int r0 = 4 * lane * 4;   // f32x4 index of row 4*lane, quarter 0
        f32x4 a0 = fn0 * WOT4[r0 + 0]  + fn1 * WOT4[r0 + 4]
                 + fn2 * WOT4[r0 + 8]  + fn3 * WOT4[r0 + 12];
        f32x4 a1 = fn0 * WOT4[r0 + 1]  + fn1 * WOT4[r0 + 5]
                 + fn2 * WOT4[r0 + 9]  + fn3 * WOT4[r0 + 13];
        f32x4 a2 = fn0 * WOT4[r0 + 2]  + fn1 * WOT4[r0 + 6]
                 + fn2 * WOT4[r0 + 10] + fn3 * WOT4[r0 + 14];
        f32x4 a3 = fn0 * WOT4[r0 + 3]  + fn1 * WOT4[r0 + 7]
                 + fn2 * WOT4[r0 + 11] + fn3 * WOT4[r0 + 15];

        #pragma unroll
        for (int off = 1; off < 64; off <<= 1) {
            f32x4 t0, t1, t2, t3;
            t0.x = __shfl_xor(a0.x, off, 64); t0.y = __shfl_xor(a0.y, off, 64);
            t0.z = __shfl_xor(a0.z, off, 64); t0.w = __shfl_xor(a0.w, off, 64);
            t1.x = __shfl_xor(a1.x, off, 64); t1.y = __shfl_xor(a1.y, off, 64);
            t1.z = __shfl_xor(a1.z, off, 64); t1.w = __shfl_xor(a1.w, off, 64);
            t2.x = __shfl_xor(a2.x, off, 64); t2.y = __shfl_xor(a2.y, off, 64);
            t2.z = __shfl_xor(a2.z, off, 64); t2.w = __shfl_xor(a2.w, off, 64);
            t3.x = __shfl_xor(a3.x, off, 64); t3.y = __shfl_xor(a3.y, off, 64);
            t3.z = __shfl_xor(a3.z, off, 64); t3.w = __shfl_xor(a3.w, off, 64);
            a0 += t0; a1 += t1; a2 += t2; a3 += t3;
        }

        int spk = n0 + n1 + n2 + n3;
        #pragma unroll
        for (int off = 1; off < 64; off <<= 1)
            spk += __shfl_xor(spk, off, 64);
        if (lane == 0) red[wv] = spk;

        if (lane < 4) {
            const f32x4 acc = (lane == 0) ? a0 : (lane == 1) ? a1
                              : (lane == 2) ? a2 : a3;
            const f32x4 bo = ((const f32x4*)b_out)[lane];
            ((f32x4*)out)[b * 4 + lane] = 32.0f * bo + acc;
        }
    }

    __syncthreads();
    if (tid == 0) {
        int s = 0;
        #pragma unroll
        for (int i = 0; i < NW; ++i) s += red[i];
        atomicAdd(counter, s);
    }
}

// ---------------------------------------------------------------------------
// K3: spikerate = count / 2^25 (exact in fp32 since count < 2^24)
// ---------------------------------------------------------------------------
__global__ void k_fin(const int* __restrict__ counter, float* __restrict__ out)
{
    out[BDIM * ODIM] = (float)(*counter) * (1.0f / 33554432.0f);
}

// ---------------------------------------------------------------------------
extern "C" void kernel_launch(void* const* d_in, const int* in_sizes, int n_in,
                              void* d_out, int out_size, void* d_ws, size_t ws_size,
                              hipStream_t stream)
{
    const int*   x     = (const int*)  d_in[0];
    const float* emb   = (const float*)d_in[1];
    const float* W_in  = (const float*)d_in[2];
    const float* W_rec = (const float*)d_in[3];
    const float* W_out = (const float*)d_in[4];
    const float* b_out = (const float*)d_in[5];
    float* out = (float*)d_out;

    float* P       = (float*)d_ws;
    float* WT      = P + P_FLOATS;
    float* WOT     = WT + WT_FLOATS;
    int*   counter = (int*)(WOT + WOT_FLOATS);

    k_prep<<<642, 256, 0, stream>>>(emb, W_in, W_rec, W_out, P, WT, WOT, counter);
    k_main<<<BDIM / NW, 1024, 0, stream>>>(x, P, WT, WOT, b_out, out, counter);
    k_fin<<<1, 1, 0, stream>>>(counter, out);
}